// Round 9
// baseline (269.613 us; speedup 1.0000x reference)
//
#include <hip/hip_runtime.h>
#include <math.h>

// d_out layout (floats): out1[N*10] | out2[N*20] | h[N*128]
//   The h region (as shorts) hosts the interleaved bf16 staging layout:
//     row r shorts [256r, 256r+128) = xb row r   (written by conv_x)
//     row r shorts [256r+128, 256r+256) = aggb row r (written by agg_gather_b)
//   gemm_fused reads both (block-row-local) and overwrites with f32 h in-place.
// d_ws (ints then shorts/floats, ~26MB):
//   G[nb*NBLK] | csum[256] | offs[N+1] | ebuf[E] | elist[E] | wbT[128*256] | wcnf[30*128]
// Radix partition: bucket = dst>>8, NBLK=128 blocks with private segments.
// Fallback: atomic-scatter fp32 path (+ separate head_kernel).

typedef __attribute__((ext_vector_type(8))) short s16x8;
typedef __attribute__((ext_vector_type(4))) float f32x4;

#define NBLK 128
#define BLKT 512
#define SH 8
#define BMASK 255

static __device__ __forceinline__ unsigned short f2b(float f) {
  unsigned u = __builtin_bit_cast(unsigned, f);
  u += 0x7fff + ((u >> 16) & 1);                 // round-to-nearest-even
  return (unsigned short)(u >> 16);
}
static __device__ __forceinline__ float b2f(unsigned short s) {
  unsigned u = ((unsigned)s) << 16;
  return __builtin_bit_cast(float, u);
}

// ---------------- radix CSR build ----------------

__global__ __launch_bounds__(BLKT) void radix_hist(
    const int* __restrict__ ei, int* __restrict__ G, int E, int nb, int CH)
{
  __shared__ int cnt[512];
  const int b = blockIdx.x;
  const int t = threadIdx.x;
  for (int i = t; i < 512; i += BLKT) cnt[i] = 0;
  __syncthreads();
  const int e0 = b * CH, e1 = min(E, e0 + CH);
  for (int e = e0 + t; e < e1; e += BLKT)
    atomicAdd(&cnt[ei[(size_t)E + e] >> SH], 1);
  __syncthreads();
  for (int k = t; k < nb; k += BLKT)
    G[(size_t)k * NBLK + b] = cnt[k];
}

#define SCAN_CHUNK 2048

__global__ __launch_bounds__(256) void scan1_kernel(
    const int* __restrict__ cnt, int* __restrict__ offs,
    int* __restrict__ csum, int n)
{
  __shared__ int s_scan[256];
  const int t = threadIdx.x;
  const int base = blockIdx.x * SCAN_CHUNK + t * 8;
  int v[8];
  int s = 0;
#pragma unroll
  for (int k = 0; k < 8; ++k) {
    v[k] = (base + k < n) ? cnt[base + k] : 0;
    s += v[k];
  }
  s_scan[t] = s;
  __syncthreads();
#pragma unroll
  for (int off = 1; off < 256; off <<= 1) {
    int add = (t >= off) ? s_scan[t - off] : 0;
    __syncthreads();
    s_scan[t] += add;
    __syncthreads();
  }
  int run = s_scan[t] - s;
#pragma unroll
  for (int k = 0; k < 8; ++k) {
    if (base + k < n) offs[base + k] = run;
    run += v[k];
  }
  if (t == 255) csum[blockIdx.x] = s_scan[255];
}

__global__ __launch_bounds__(256) void scan2_kernel(int* __restrict__ csum, int nc)
{
  __shared__ int s_scan[256];
  const int t = threadIdx.x;
  int c = (t < nc) ? csum[t] : 0;
  s_scan[t] = c;
  __syncthreads();
#pragma unroll
  for (int off = 1; off < 256; off <<= 1) {
    int add = (t >= off) ? s_scan[t - off] : 0;
    __syncthreads();
    s_scan[t] += add;
    __syncthreads();
  }
  if (t < nc) csum[t] = s_scan[t] - c;
}

__global__ __launch_bounds__(256) void scan3_add(
    int* __restrict__ G, const int* __restrict__ csum, int n)
{
  int i = blockIdx.x * blockDim.x + threadIdx.x;
  if (i < n) G[i] += csum[i / SCAN_CHUNK];
}

__global__ __launch_bounds__(BLKT) void radix_scatter(
    const int* __restrict__ ei, const int* __restrict__ G,
    int* __restrict__ ebuf, int E, int nb, int CH)
{
  __shared__ int cur[512];
  const int b = blockIdx.x;
  const int t = threadIdx.x;
  for (int k = t; k < nb; k += BLKT) cur[k] = G[(size_t)k * NBLK + b];
  __syncthreads();
  const int e0 = b * CH, e1 = min(E, e0 + CH);
  for (int e = e0 + t; e < e1; e += BLKT) {
    int src = ei[e];
    int dst = ei[(size_t)E + e];
    int pos = atomicAdd(&cur[dst >> SH], 1);
    ebuf[pos] = (src << SH) | (dst & BMASK);
  }
}

__global__ __launch_bounds__(256) void csr_finalize(
    const int* __restrict__ G, const int* __restrict__ ebuf,
    int* __restrict__ offs, int* __restrict__ elist, int N, int E, int nb)
{
  __shared__ int cnt[256];
  __shared__ int sc[256];
  __shared__ int cur[256];
  const int b = blockIdx.x;
  const int t = threadIdx.x;
  const int e0 = G[(size_t)b * NBLK];
  const int e1 = (b + 1 < nb) ? G[(size_t)(b + 1) * NBLK] : E;

  cnt[t] = 0;
  __syncthreads();
  for (int j = e0 + t; j < e1; j += 256)
    atomicAdd(&cnt[ebuf[j] & BMASK], 1);
  __syncthreads();
  int v = cnt[t];
  sc[t] = v;
  __syncthreads();
#pragma unroll
  for (int off = 1; off < 256; off <<= 1) {
    int add = (t >= off) ? sc[t - off] : 0;
    __syncthreads();
    sc[t] += add;
    __syncthreads();
  }
  int ex = e0 + sc[t] - v;
  int node = (b << SH) + t;
  if (node < N) offs[node] = ex;
  cur[t] = ex;
  if (b == 0 && t == 0) offs[N] = E;
  __syncthreads();
  for (int j = e0 + t; j < e1; j += 256) {
    int w = ebuf[j];
    int pos = atomicAdd(&cur[w & BMASK], 1);
    elist[pos] = w >> SH;
  }
}

// ---------------- bf16 x into interleaved h region ----------------

__global__ __launch_bounds__(256) void conv_x_kernel(
    const float* __restrict__ x, short* __restrict__ hs, int n8)
{
  int stride = gridDim.x * blockDim.x;
  for (int i = blockIdx.x * blockDim.x + threadIdx.x; i < n8; i += stride) {
    int row = i >> 4, seg = i & 15;
    float4 v0 = ((const float4*)x)[(size_t)row * 32 + seg * 2];
    float4 v1 = ((const float4*)x)[(size_t)row * 32 + seg * 2 + 1];
    s16x8 o;
    o[0] = (short)f2b(v0.x); o[1] = (short)f2b(v0.y);
    o[2] = (short)f2b(v0.z); o[3] = (short)f2b(v0.w);
    o[4] = (short)f2b(v1.x); o[5] = (short)f2b(v1.y);
    o[6] = (short)f2b(v1.z); o[7] = (short)f2b(v1.w);
    *(s16x8*)&hs[(size_t)row * 256 + seg * 8] = o;
  }
}

// ---------------- gather (bf16 x half, fp32 accum, mean, bf16 agg half) -----

__global__ __launch_bounds__(256) void agg_gather_b(
    const short* __restrict__ hs_in, short* __restrict__ hs_out,
    const int* __restrict__ offs, const int* __restrict__ elist, int N)
{
  const int lane = threadIdx.x & 63;
  const int row = blockIdx.x * 4 + (threadIdx.x >> 6);
  if (row >= N) return;
  const int qt = lane >> 4;     // edge slot 0..3
  const int c  = lane & 15;     // 8-bf16 segment
  const int start = offs[row], end = offs[row + 1];
  float a[8] = {0.f, 0.f, 0.f, 0.f, 0.f, 0.f, 0.f, 0.f};
  for (int j = start + qt; j < end; j += 4) {
    const s16x8 v = *(const s16x8*)&hs_in[(size_t)elist[j] * 256 + c * 8];
#pragma unroll
    for (int k = 0; k < 8; ++k) a[k] += b2f((unsigned short)v[k]);
  }
#pragma unroll
  for (int k = 0; k < 8; ++k) {
    a[k] += __shfl_xor(a[k], 16);
    a[k] += __shfl_xor(a[k], 32);
  }
  if (qt == 0) {
    float rd = 1.0f / fmaxf((float)(end - start), 1.0f);
    s16x8 o;
#pragma unroll
    for (int k = 0; k < 8; ++k) o[k] = (short)f2b(a[k] * rd);
    *(s16x8*)&hs_out[(size_t)row * 256 + 128 + c * 8] = o;
  }
}

// wbT[c][k]: k=0..127 from Wr (x half), k=128..255 from Wl (agg half)
__global__ __launch_bounds__(256) void conv_w_kernel(
    const float* __restrict__ Wl, const float* __restrict__ Wr,
    short* __restrict__ wbT)
{
  int i = blockIdx.x * blockDim.x + threadIdx.x;
  if (i < 128 * 256) {
    int c = i >> 8;
    int k = i & 255;
    float v = (k < 128) ? Wr[(size_t)k * 128 + c] : Wl[(size_t)(k - 128) * 128 + c];
    wbT[i] = (short)f2b(v);
  }
}

// normalized head weights, f32: wcnf[j][l], j<30 (10 from W1, 20 from W2)
__global__ __launch_bounds__(128) void conv_wcn(
    const float* __restrict__ W1, const float* __restrict__ W2,
    float* __restrict__ wcnf, int c1, int c2)
{
  int j = blockIdx.x;
  int l = threadIdx.x;
  const float* W;
  int cols, col;
  if (j < c1) { W = W1; cols = c1; col = j; }
  else        { W = W2; cols = c2; col = j - c1; }
  float v = W[(size_t)l * cols + col];
  float ss = v * v;
#pragma unroll
  for (int m = 1; m <= 32; m <<= 1) ss += __shfl_xor(ss, m);
  __shared__ float sred[2];
  if ((l & 63) == 0) sred[l >> 6] = ss;
  __syncthreads();
  float n = sqrtf(sred[0] + sred[1]);
  wcnf[(size_t)j * 128 + l] = v / fmaxf(n, 1e-12f);
}

// ---------------- fused MFMA gemm + heads ----------------
// h = [x|agg] @ wbT^T + bl  (K=256, interleaved bf16 A rows, in-place over hs),
// then per-row norm + 30-col head matmul in the same block.

__global__ __launch_bounds__(256, 2) void gemm_fused(
    const short* __restrict__ hs, const short* __restrict__ wbT,
    const float* __restrict__ bl, const float* __restrict__ wcnf,
    float* __restrict__ h, float* __restrict__ out1, float* __restrict__ out2,
    int N)
{
  __shared__ __align__(16) char smem[68608];
  short (*A_s)[72] = reinterpret_cast<short(*)[72]>(smem);          // 18432B
  short (*B_s)[72] = reinterpret_cast<short(*)[72]>(smem + 18432);  // 18432B
  float (*H_s)[132] = reinterpret_cast<float(*)[132]>(smem);        // 67584B
  float (*rowss)[128] = reinterpret_cast<float(*)[128]>(smem + 67584); // 2x128x4

  const int t = threadIdx.x;
  const int lane = t & 63;
  const int wid = t >> 6;
  const int wr = wid >> 1;
  const int wc = wid & 1;
  const int row0 = blockIdx.x * 128;
  const int l15 = lane & 15;
  const int lhi = lane >> 4;

  f32x4 acc[4][4];
#pragma unroll
  for (int m = 0; m < 4; ++m)
#pragma unroll
    for (int n = 0; n < 4; ++n) acc[m][n] = (f32x4){0.f, 0.f, 0.f, 0.f};

  for (int kc = 0; kc < 4; ++kc) {
    __syncthreads();
#pragma unroll
    for (int uu = 0; uu < 4; ++uu) {
      int u = t + uu * 256;        // 0..1023
      int r = u >> 3;              // row 0..127
      int s = u & 7;               // 8-short segment 0..7
      s16x8 va = {0, 0, 0, 0, 0, 0, 0, 0};
      int grow = row0 + r;
      if (grow < N)
        va = *(const s16x8*)&hs[(size_t)grow * 256 + kc * 64 + s * 8];
      *(s16x8*)&A_s[r][s * 8] = va;
      s16x8 vb = *(const s16x8*)&wbT[(size_t)r * 256 + kc * 64 + s * 8];
      *(s16x8*)&B_s[r][s * 8] = vb;
    }
    __syncthreads();

#pragma unroll
    for (int ks = 0; ks < 64; ks += 32) {
      const int klo = ks + lhi * 8;
      s16x8 af[4], bf[4];
#pragma unroll
      for (int m = 0; m < 4; ++m)
        af[m] = *(const s16x8*)&A_s[wr * 64 + m * 16 + l15][klo];
#pragma unroll
      for (int n = 0; n < 4; ++n)
        bf[n] = *(const s16x8*)&B_s[wc * 64 + n * 16 + l15][klo];
#pragma unroll
      for (int m = 0; m < 4; ++m)
#pragma unroll
        for (int n = 0; n < 4; ++n)
          acc[m][n] = __builtin_amdgcn_mfma_f32_16x16x32_bf16(
              af[m], bf[n], acc[m][n], 0, 0, 0);
    }
  }

  // barrier: all A_s/B_s LDS reads done before H_s overwrites the same bytes
  __syncthreads();

  // epilogue 1: bias, f32 h to global + H_s, per-row sum-of-squares
  float bcol[4];
#pragma unroll
  for (int n = 0; n < 4; ++n) bcol[n] = bl[wc * 64 + n * 16 + l15];
#pragma unroll
  for (int m = 0; m < 4; ++m) {
#pragma unroll
    for (int r = 0; r < 4; ++r) {
      int lr = wr * 64 + m * 16 + lhi * 4 + r;
      int grow = row0 + lr;
      float hv[4];
      float ps = 0.f;
#pragma unroll
      for (int n = 0; n < 4; ++n) {
        hv[n] = acc[m][n][r] + bcol[n];
        ps += hv[n] * hv[n];
      }
#pragma unroll
      for (int mask = 1; mask < 16; mask <<= 1) ps += __shfl_xor(ps, mask);
      if (grow < N) {
#pragma unroll
        for (int n = 0; n < 4; ++n) {
          int col = wc * 64 + n * 16 + l15;
          H_s[lr][col] = hv[n];
          h[(size_t)grow * 128 + col] = hv[n];
        }
        if (l15 == 0) rowss[wc][lr] = ps;
      }
    }
  }
  __syncthreads();

  // epilogue 2: heads. 2 threads per row, 15 cols each. wcnf from global (L1-hot).
  {
    int row = t >> 1;
    int half = t & 1;
    int grow = row0 + row;
    if (grow < N) {
      float sc = 10.0f / fmaxf(sqrtf(rowss[0][row] + rowss[1][row]), 1e-12f);
      float acch[15];
#pragma unroll
      for (int j = 0; j < 15; ++j) acch[j] = 0.f;
      for (int k = 0; k < 128; k += 4) {
        float4 hv = *(const float4*)&H_s[row][k];
#pragma unroll
        for (int j = 0; j < 15; ++j) {
          const float4 w = *(const float4*)&wcnf[(size_t)(half * 15 + j) * 128 + k];
          acch[j] += hv.x * w.x + hv.y * w.y + hv.z * w.z + hv.w * w.w;
        }
      }
#pragma unroll
      for (int j = 0; j < 15; ++j) {
        int jj = half * 15 + j;
        float o = sc * acch[j];
        if (jj < 10) out1[(size_t)grow * 10 + jj] = o;
        else         out2[(size_t)grow * 20 + (jj - 10)] = o;
      }
    }
  }
}

// ---------------- fallback: atomic scatter + fp32 gemm + head ----------------

__global__ __launch_bounds__(256) void edge_scatter(
    const float* __restrict__ x, const int* __restrict__ ei,
    float* __restrict__ agg, float* __restrict__ deg, int E)
{
  long long total = (long long)E * 32;
  long long stride = (long long)gridDim.x * blockDim.x;
  for (long long i = (long long)blockIdx.x * blockDim.x + threadIdx.x;
       i < total; i += stride) {
    int e = (int)(i >> 5);
    int c = (int)(i & 31);
    int src = ei[e];
    int dst = ei[(size_t)E + e];
    float4 v = ((const float4*)x)[(size_t)src * 32 + c];
    float* a = agg + (size_t)dst * 128 + c * 4;
    atomicAdd(a + 0, v.x);
    atomicAdd(a + 1, v.y);
    atomicAdd(a + 2, v.z);
    atomicAdd(a + 3, v.w);
    if (c == 0) atomicAdd(deg + dst, 1.0f);
  }
}

#define FMA4(accR, wv, s) { accR[0] += (s) * wv.x; accR[1] += (s) * wv.y; \
                            accR[2] += (s) * wv.z; accR[3] += (s) * wv.w; }

__global__ __launch_bounds__(256, 2) void gemm_h(
    const float* __restrict__ x, const float* __restrict__ Wl,
    const float* __restrict__ bl, const float* __restrict__ Wr,
    const float* __restrict__ degf, float* __restrict__ aggh, int N)
{
  __shared__ float a_s[128][36];
  __shared__ float x_s[128][36];
  __shared__ float wl_s[32][128];
  __shared__ float wr_s[32][128];

  const int t = threadIdx.x;
  const int tx = t & 15;
  const int ty = t >> 4;
  const int row0 = blockIdx.x * 128;

  float acc0[8][4];
  float acc1[8][4];
#pragma unroll
  for (int r = 0; r < 8; ++r)
#pragma unroll
    for (int c = 0; c < 4; ++c) { acc0[r][c] = 0.f; acc1[r][c] = 0.f; }

  for (int kc = 0; kc < 4; ++kc) {
    __syncthreads();
#pragma unroll
    for (int j = 0; j < 4; ++j) {
      int i = t + 256 * j;
      int r = i >> 3;
      int c4 = i & 7;
      int row = row0 + r;
      float4 av = {0.f, 0.f, 0.f, 0.f};
      float4 xv = {0.f, 0.f, 0.f, 0.f};
      if (row < N) {
        float rd = 1.0f / fmaxf(degf[row], 1.0f);
        av = ((const float4*)aggh)[(size_t)row * 32 + kc * 8 + c4];
        av.x *= rd; av.y *= rd; av.z *= rd; av.w *= rd;
        xv = ((const float4*)x)[(size_t)row * 32 + kc * 8 + c4];
      }
      *(float4*)&a_s[r][c4 * 4] = av;
      *(float4*)&x_s[r][c4 * 4] = xv;
    }
#pragma unroll
    for (int j = 0; j < 4; ++j) {
      int i = t + 256 * j;
      int kk = i >> 5;
      int c4 = i & 31;
      ((float4*)wl_s[kk])[c4] = ((const float4*)Wl)[(size_t)(kc * 32 + kk) * 32 + c4];
      ((float4*)wr_s[kk])[c4] = ((const float4*)Wr)[(size_t)(kc * 32 + kk) * 32 + c4];
    }
    __syncthreads();

#pragma unroll
    for (int k4 = 0; k4 < 8; ++k4) {
      float4 wl0[4], wl1[4], wr0[4], wr1[4];
#pragma unroll
      for (int kk = 0; kk < 4; ++kk) {
        int k = k4 * 4 + kk;
        wl0[kk] = *(const float4*)&wl_s[k][tx * 4];
        wl1[kk] = *(const float4*)&wl_s[k][64 + tx * 4];
        wr0[kk] = *(const float4*)&wr_s[k][tx * 4];
        wr1[kk] = *(const float4*)&wr_s[k][64 + tx * 4];
      }
#pragma unroll
      for (int r = 0; r < 8; ++r) {
        int rr = ty + 16 * r;
        float4 a  = *(const float4*)&a_s[rr][k4 * 4];
        float4 xv = *(const float4*)&x_s[rr][k4 * 4];
        FMA4(acc0[r], wl0[0], a.x); FMA4(acc0[r], wl0[1], a.y);
        FMA4(acc0[r], wl0[2], a.z); FMA4(acc0[r], wl0[3], a.w);
        FMA4(acc0[r], wr0[0], xv.x); FMA4(acc0[r], wr0[1], xv.y);
        FMA4(acc0[r], wr0[2], xv.z); FMA4(acc0[r], wr0[3], xv.w);
        FMA4(acc1[r], wl1[0], a.x); FMA4(acc1[r], wl1[1], a.y);
        FMA4(acc1[r], wl1[2], a.z); FMA4(acc1[r], wl1[3], a.w);
        FMA4(acc1[r], wr1[0], xv.x); FMA4(acc1[r], wr1[1], xv.y);
        FMA4(acc1[r], wr1[2], xv.z); FMA4(acc1[r], wr1[3], xv.w);
      }
    }
  }

  float4 b0 = ((const float4*)bl)[tx];
  float4 b1 = ((const float4*)bl)[16 + tx];
#pragma unroll
  for (int r = 0; r < 8; ++r) {
    int row = row0 + ty + 16 * r;
    if (row < N) {
      float4 o0 = { acc0[r][0] + b0.x, acc0[r][1] + b0.y,
                    acc0[r][2] + b0.z, acc0[r][3] + b0.w };
      float4 o1 = { acc1[r][0] + b1.x, acc1[r][1] + b1.y,
                    acc1[r][2] + b1.z, acc1[r][3] + b1.w };
      ((float4*)aggh)[(size_t)row * 32 + tx] = o0;
      ((float4*)aggh)[(size_t)row * 32 + 16 + tx] = o1;
    }
  }
}

__global__ __launch_bounds__(256) void head_kernel(
    const float* __restrict__ h, const float* __restrict__ W1,
    const float* __restrict__ W2,
    float* __restrict__ out1, float* __restrict__ out2,
    int N, int c1, int c2)
{
  __shared__ float wc_s[30][132];
  __shared__ float wnorm[30];
  const int nc = c1 + c2;

  for (int i = threadIdx.x; i < nc * 128; i += 256) {
    int j = i >> 7, l = i & 127;
    wc_s[j][l] = (j < c1) ? W1[(size_t)l * c1 + j]
                          : W2[(size_t)l * c2 + (j - c1)];
  }
  __syncthreads();
  if (threadIdx.x < nc) {
    float ss = 0.f;
    for (int l = 0; l < 128; ++l) { float v = wc_s[threadIdx.x][l]; ss += v * v; }
    wnorm[threadIdx.x] = 1.0f / fmaxf(sqrtf(ss), 1e-12f);
  }
  __syncthreads();
  for (int i = threadIdx.x; i < nc * 128; i += 256) {
    int j = i >> 7;
    wc_s[j][i & 127] *= wnorm[j];
  }
  __syncthreads();

  int row = blockIdx.x * 256 + threadIdx.x;
  if (row >= N) return;
  const float4* h4 = (const float4*)(h + (size_t)row * 128);
  float acc[30];
#pragma unroll
  for (int j = 0; j < 30; ++j) acc[j] = 0.f;
  float ss = 0.f;
#pragma unroll 4
  for (int kk = 0; kk < 32; ++kk) {
    float4 v = h4[kk];
    ss += v.x * v.x + v.y * v.y + v.z * v.z + v.w * v.w;
#pragma unroll
    for (int j = 0; j < 30; ++j) {
      const float4 w = *(const float4*)&wc_s[j][kk * 4];
      acc[j] += v.x * w.x + v.y * w.y + v.z * w.z + v.w * w.w;
    }
  }
  float scale = 10.0f / fmaxf(sqrtf(ss), 1e-12f);
#pragma unroll
  for (int j = 0; j < 10; ++j) out1[(size_t)row * 10 + j] = scale * acc[j];
#pragma unroll
  for (int j = 0; j < 20; ++j) out2[(size_t)row * 20 + j] = scale * acc[10 + j];
}

// ---------------- launch ----------------

extern "C" void kernel_launch(void* const* d_in, const int* in_sizes, int n_in,
                              void* d_out, int out_size, void* d_ws, size_t ws_size,
                              hipStream_t stream)
{
  const float* x  = (const float*)d_in[0];
  const int*   ei = (const int*)d_in[1];
  const float* Wl = (const float*)d_in[2];
  const float* bl = (const float*)d_in[3];
  const float* Wr = (const float*)d_in[4];
  const float* W1 = (const float*)d_in[5];
  const float* W2 = (const float*)d_in[6];

  const int N  = in_sizes[0] / 128;
  const int E  = in_sizes[1] / 2;
  const int c1 = in_sizes[5] / 128;
  const int c2 = in_sizes[6] / 128;
  const int nb = (N + 255) >> SH;          // 256-node buckets
  const int nbk = nb * NBLK;
  const int CH = (E + NBLK - 1) / NBLK;

  float* out1 = (float*)d_out;
  float* out2 = out1 + (size_t)N * c1;
  float* h    = out2 + (size_t)N * c2;

  size_t ints = (size_t)nbk + 256 + (N + 1) + 2 * (size_t)E;
  ints = (ints + 3) & ~(size_t)3;
  const size_t need = ints * sizeof(int)
                    + (size_t)128 * 256 * sizeof(short)      // wbT
                    + (size_t)30 * 128 * sizeof(float);      // wcnf

  if (ws_size >= need && nb <= 512 && c1 == 10 && c2 == 20) {
    int* G     = (int*)d_ws;                    // nbk
    int* csum  = G + nbk;                       // 256
    int* offs  = csum + 256;                    // N+1
    int* ebuf  = offs + (N + 1);                // E packed (src<<8)|dstLow
    int* elist = ebuf + E;                      // E
    short* wbT  = (short*)((int*)d_ws + ints);  // 128*256 (16B-aligned)
    float* wcnf = (float*)(wbT + 128 * 256);    // 30*128
    short* hs   = (short*)h;                    // interleaved [xb|aggb] rows
    const int nchunks = (nbk + SCAN_CHUNK - 1) / SCAN_CHUNK;

    conv_x_kernel<<<2048, 256, 0, stream>>>(x, hs, N * 16);
    radix_hist<<<NBLK, BLKT, 0, stream>>>(ei, G, E, nb, CH);
    scan1_kernel<<<nchunks, 256, 0, stream>>>(G, G, csum, nbk);
    scan2_kernel<<<1, 256, 0, stream>>>(csum, nchunks);
    scan3_add<<<(nbk + 255) / 256, 256, 0, stream>>>(G, csum, nbk);
    radix_scatter<<<NBLK, BLKT, 0, stream>>>(ei, G, ebuf, E, nb, CH);
    csr_finalize<<<nb, 256, 0, stream>>>(G, ebuf, offs, elist, N, E, nb);
    agg_gather_b<<<(N + 3) / 4, 256, 0, stream>>>(hs, hs, offs, elist, N);
    conv_w_kernel<<<128, 256, 0, stream>>>(Wl, Wr, wbT);
    conv_wcn<<<c1 + c2, 128, 0, stream>>>(W1, W2, wcnf, c1, c2);
    gemm_fused<<<(N + 127) / 128, 256, 0, stream>>>(
        hs, wbT, bl, wcnf, h, out1, out2, N);
  } else {
    float* deg = out1;   // borrow out1 region (consumed before head rewrites it)
    hipMemsetAsync(h,   0, (size_t)N * 128 * sizeof(float), stream);
    hipMemsetAsync(deg, 0, (size_t)N * sizeof(float), stream);
    edge_scatter<<<4096, 256, 0, stream>>>(x, ei, h, deg, E);
    gemm_h<<<(N + 127) / 128, 256, 0, stream>>>(x, Wl, bl, Wr, deg, h, N);
    head_kernel<<<(N + 255) / 256, 256, 0, stream>>>(h, W1, W2, out1, out2, N, c1, c2);
  }
}

// Round 10
// 193.558 us; speedup vs baseline: 1.3929x; 1.3929x over previous
//
#include <hip/hip_runtime.h>
#include <math.h>

// d_out layout (floats): out1[N*10] | out2[N*20] | h[N*128]
//   The h region (as shorts) hosts the interleaved bf16 staging layout:
//     row r shorts [256r, 256r+128)    = xb row r    (written by conv_x)
//     row r shorts [256r+128, 256r+256) = aggb row r (written by agg_gather_b)
//   gemm_mfma reads block-local rows and overwrites them with f32 h in-place.
// d_ws (~26MB):
//   G[nb*NBLK] | csum[256] | offs[N+1] | ebuf[E] | elist[E] | wbT[128*256]
// Radix partition: bucket = dst>>8, NBLK=128 blocks with private segments.
// Fallback: atomic-scatter fp32 path (+ separate gemm_h / head_kernel).

typedef __attribute__((ext_vector_type(8))) short s16x8;
typedef __attribute__((ext_vector_type(4))) float f32x4;

#define NBLK 128
#define BLKT 512
#define SH 8
#define BMASK 255

static __device__ __forceinline__ unsigned short f2b(float f) {
  unsigned u = __builtin_bit_cast(unsigned, f);
  u += 0x7fff + ((u >> 16) & 1);                 // round-to-nearest-even
  return (unsigned short)(u >> 16);
}
static __device__ __forceinline__ float b2f(unsigned short s) {
  unsigned u = ((unsigned)s) << 16;
  return __builtin_bit_cast(float, u);
}

// ---------------- radix CSR build ----------------

__global__ __launch_bounds__(BLKT) void radix_hist(
    const int* __restrict__ ei, int* __restrict__ G, int E, int nb, int CH)
{
  __shared__ int cnt[512];
  const int b = blockIdx.x;
  const int t = threadIdx.x;
  for (int i = t; i < 512; i += BLKT) cnt[i] = 0;
  __syncthreads();
  const int e0 = b * CH, e1 = min(E, e0 + CH);
  for (int e = e0 + t; e < e1; e += BLKT)
    atomicAdd(&cnt[ei[(size_t)E + e] >> SH], 1);
  __syncthreads();
  for (int k = t; k < nb; k += BLKT)
    G[(size_t)k * NBLK + b] = cnt[k];
}

#define SCAN_CHUNK 2048

__global__ __launch_bounds__(256) void scan1_kernel(
    const int* __restrict__ cnt, int* __restrict__ offs,
    int* __restrict__ csum, int n)
{
  __shared__ int s_scan[256];
  const int t = threadIdx.x;
  const int base = blockIdx.x * SCAN_CHUNK + t * 8;
  int v[8];
  int s = 0;
#pragma unroll
  for (int k = 0; k < 8; ++k) {
    v[k] = (base + k < n) ? cnt[base + k] : 0;
    s += v[k];
  }
  s_scan[t] = s;
  __syncthreads();
#pragma unroll
  for (int off = 1; off < 256; off <<= 1) {
    int add = (t >= off) ? s_scan[t - off] : 0;
    __syncthreads();
    s_scan[t] += add;
    __syncthreads();
  }
  int run = s_scan[t] - s;
#pragma unroll
  for (int k = 0; k < 8; ++k) {
    if (base + k < n) offs[base + k] = run;
    run += v[k];
  }
  if (t == 255) csum[blockIdx.x] = s_scan[255];
}

__global__ __launch_bounds__(256) void scan2_kernel(int* __restrict__ csum, int nc)
{
  __shared__ int s_scan[256];
  const int t = threadIdx.x;
  int c = (t < nc) ? csum[t] : 0;
  s_scan[t] = c;
  __syncthreads();
#pragma unroll
  for (int off = 1; off < 256; off <<= 1) {
    int add = (t >= off) ? s_scan[t - off] : 0;
    __syncthreads();
    s_scan[t] += add;
    __syncthreads();
  }
  if (t < nc) csum[t] = s_scan[t] - c;
}

__global__ __launch_bounds__(256) void scan3_add(
    int* __restrict__ G, const int* __restrict__ csum, int n)
{
  int i = blockIdx.x * blockDim.x + threadIdx.x;
  if (i < n) G[i] += csum[i / SCAN_CHUNK];
}

__global__ __launch_bounds__(BLKT) void radix_scatter(
    const int* __restrict__ ei, const int* __restrict__ G,
    int* __restrict__ ebuf, int E, int nb, int CH)
{
  __shared__ int cur[512];
  const int b = blockIdx.x;
  const int t = threadIdx.x;
  for (int k = t; k < nb; k += BLKT) cur[k] = G[(size_t)k * NBLK + b];
  __syncthreads();
  const int e0 = b * CH, e1 = min(E, e0 + CH);
  for (int e = e0 + t; e < e1; e += BLKT) {
    int src = ei[e];
    int dst = ei[(size_t)E + e];
    int pos = atomicAdd(&cur[dst >> SH], 1);
    ebuf[pos] = (src << SH) | (dst & BMASK);
  }
}

__global__ __launch_bounds__(256) void csr_finalize(
    const int* __restrict__ G, const int* __restrict__ ebuf,
    int* __restrict__ offs, int* __restrict__ elist, int N, int E, int nb)
{
  __shared__ int cnt[256];
  __shared__ int sc[256];
  __shared__ int cur[256];
  const int b = blockIdx.x;
  const int t = threadIdx.x;
  const int e0 = G[(size_t)b * NBLK];
  const int e1 = (b + 1 < nb) ? G[(size_t)(b + 1) * NBLK] : E;

  cnt[t] = 0;
  __syncthreads();
  for (int j = e0 + t; j < e1; j += 256)
    atomicAdd(&cnt[ebuf[j] & BMASK], 1);
  __syncthreads();
  int v = cnt[t];
  sc[t] = v;
  __syncthreads();
#pragma unroll
  for (int off = 1; off < 256; off <<= 1) {
    int add = (t >= off) ? sc[t - off] : 0;
    __syncthreads();
    sc[t] += add;
    __syncthreads();
  }
  int ex = e0 + sc[t] - v;
  int node = (b << SH) + t;
  if (node < N) offs[node] = ex;
  cur[t] = ex;
  if (b == 0 && t == 0) offs[N] = E;
  __syncthreads();
  for (int j = e0 + t; j < e1; j += 256) {
    int w = ebuf[j];
    int pos = atomicAdd(&cur[w & BMASK], 1);
    elist[pos] = w >> SH;
  }
}

// ---------------- bf16 x into interleaved h region ----------------

__global__ __launch_bounds__(256) void conv_x_kernel(
    const float* __restrict__ x, short* __restrict__ hs, int n8)
{
  int stride = gridDim.x * blockDim.x;
  for (int i = blockIdx.x * blockDim.x + threadIdx.x; i < n8; i += stride) {
    int row = i >> 4, seg = i & 15;
    float4 v0 = ((const float4*)x)[(size_t)row * 32 + seg * 2];
    float4 v1 = ((const float4*)x)[(size_t)row * 32 + seg * 2 + 1];
    s16x8 o;
    o[0] = (short)f2b(v0.x); o[1] = (short)f2b(v0.y);
    o[2] = (short)f2b(v0.z); o[3] = (short)f2b(v0.w);
    o[4] = (short)f2b(v1.x); o[5] = (short)f2b(v1.y);
    o[6] = (short)f2b(v1.z); o[7] = (short)f2b(v1.w);
    *(s16x8*)&hs[(size_t)row * 256 + seg * 8] = o;
  }
}

// ---------------- gather (bf16 x half, fp32 accum, mean, bf16 agg half) -----

__global__ __launch_bounds__(256) void agg_gather_b(
    const short* __restrict__ hs_in, short* __restrict__ hs_out,
    const int* __restrict__ offs, const int* __restrict__ elist, int N)
{
  const int lane = threadIdx.x & 63;
  const int row = blockIdx.x * 4 + (threadIdx.x >> 6);
  if (row >= N) return;
  const int qt = lane >> 4;     // edge slot 0..3
  const int c  = lane & 15;     // 8-bf16 segment
  const int start = offs[row], end = offs[row + 1];
  float a[8] = {0.f, 0.f, 0.f, 0.f, 0.f, 0.f, 0.f, 0.f};
  for (int j = start + qt; j < end; j += 4) {
    const s16x8 v = *(const s16x8*)&hs_in[(size_t)elist[j] * 256 + c * 8];
#pragma unroll
    for (int k = 0; k < 8; ++k) a[k] += b2f((unsigned short)v[k]);
  }
#pragma unroll
  for (int k = 0; k < 8; ++k) {
    a[k] += __shfl_xor(a[k], 16);
    a[k] += __shfl_xor(a[k], 32);
  }
  if (qt == 0) {
    float rd = 1.0f / fmaxf((float)(end - start), 1.0f);
    s16x8 o;
#pragma unroll
    for (int k = 0; k < 8; ++k) o[k] = (short)f2b(a[k] * rd);
    *(s16x8*)&hs_out[(size_t)row * 256 + 128 + c * 8] = o;
  }
}

// wbT[c][k]: k=0..127 from Wr (x half), k=128..255 from Wl (agg half)
__global__ __launch_bounds__(256) void conv_w_kernel(
    const float* __restrict__ Wl, const float* __restrict__ Wr,
    short* __restrict__ wbT)
{
  int i = blockIdx.x * blockDim.x + threadIdx.x;
  if (i < 128 * 256) {
    int c = i >> 8;
    int k = i & 255;
    float v = (k < 128) ? Wr[(size_t)k * 128 + c] : Wl[(size_t)(k - 128) * 128 + c];
    wbT[i] = (short)f2b(v);
  }
}

// ---------------- MFMA gemm: h = [x|agg] @ wbT^T + bl (in-place over hs) ----

__global__ __launch_bounds__(256, 2) void gemm_mfma(
    const short* __restrict__ hs, const short* __restrict__ wbT,
    const float* __restrict__ bl, float* __restrict__ h, int N)
{
  __shared__ short A_s[128][72];   // +8 bf16 pad
  __shared__ short B_s[128][72];   // B_s[col][k]

  const int t = threadIdx.x;
  const int lane = t & 63;
  const int wid = t >> 6;
  const int wr = wid >> 1;
  const int wc = wid & 1;
  const int row0 = blockIdx.x * 128;
  const int l15 = lane & 15;
  const int lhi = lane >> 4;

  f32x4 acc[4][4];
#pragma unroll
  for (int m = 0; m < 4; ++m)
#pragma unroll
    for (int n = 0; n < 4; ++n) acc[m][n] = (f32x4){0.f, 0.f, 0.f, 0.f};

  for (int kc = 0; kc < 4; ++kc) {
    __syncthreads();
#pragma unroll
    for (int uu = 0; uu < 4; ++uu) {
      int u = t + uu * 256;        // 0..1023
      int r = u >> 3;              // row 0..127
      int s = u & 7;               // 8-short segment 0..7
      s16x8 va = {0, 0, 0, 0, 0, 0, 0, 0};
      int grow = row0 + r;
      if (grow < N)
        va = *(const s16x8*)&hs[(size_t)grow * 256 + kc * 64 + s * 8];
      *(s16x8*)&A_s[r][s * 8] = va;
      s16x8 vb = *(const s16x8*)&wbT[(size_t)r * 256 + kc * 64 + s * 8];
      *(s16x8*)&B_s[r][s * 8] = vb;
    }
    __syncthreads();

#pragma unroll
    for (int ks = 0; ks < 64; ks += 32) {
      const int klo = ks + lhi * 8;
      s16x8 af[4], bf[4];
#pragma unroll
      for (int m = 0; m < 4; ++m)
        af[m] = *(const s16x8*)&A_s[wr * 64 + m * 16 + l15][klo];
#pragma unroll
      for (int n = 0; n < 4; ++n)
        bf[n] = *(const s16x8*)&B_s[wc * 64 + n * 16 + l15][klo];
#pragma unroll
      for (int m = 0; m < 4; ++m)
#pragma unroll
        for (int n = 0; n < 4; ++n)
          acc[m][n] = __builtin_amdgcn_mfma_f32_16x16x32_bf16(
              af[m], bf[n], acc[m][n], 0, 0, 0);
    }
  }

  // C frag mapping: col=lane&15, row=(lane>>4)*4+reg (m89-verified)
  float bcol[4];
#pragma unroll
  for (int n = 0; n < 4; ++n) bcol[n] = bl[wc * 64 + n * 16 + l15];
#pragma unroll
  for (int m = 0; m < 4; ++m) {
    int grow_base = row0 + wr * 64 + m * 16 + lhi * 4;
#pragma unroll
    for (int r = 0; r < 4; ++r) {
      int grow = grow_base + r;
      if (grow < N) {
#pragma unroll
        for (int n = 0; n < 4; ++n) {
          int col = wc * 64 + n * 16 + l15;
          h[(size_t)grow * 128 + col] = acc[m][n][r] + bcol[n];
        }
      }
    }
  }
}

// ---------------- heads (one thread per row, wc_s broadcast) ----------------

__global__ __launch_bounds__(256) void head_kernel(
    const float* __restrict__ h, const float* __restrict__ W1,
    const float* __restrict__ W2,
    float* __restrict__ out1, float* __restrict__ out2,
    int N, int c1, int c2)
{
  __shared__ float wc_s[30][132];
  __shared__ float wnorm[30];
  const int nc = c1 + c2;

  for (int i = threadIdx.x; i < nc * 128; i += 256) {
    int j = i >> 7, l = i & 127;
    wc_s[j][l] = (j < c1) ? W1[(size_t)l * c1 + j]
                          : W2[(size_t)l * c2 + (j - c1)];
  }
  __syncthreads();
  if (threadIdx.x < nc) {
    float ss = 0.f;
    for (int l = 0; l < 128; ++l) { float v = wc_s[threadIdx.x][l]; ss += v * v; }
    wnorm[threadIdx.x] = 1.0f / fmaxf(sqrtf(ss), 1e-12f);
  }
  __syncthreads();
  for (int i = threadIdx.x; i < nc * 128; i += 256) {
    int j = i >> 7;
    wc_s[j][i & 127] *= wnorm[j];
  }
  __syncthreads();

  int row = blockIdx.x * 256 + threadIdx.x;
  if (row >= N) return;
  const float4* h4 = (const float4*)(h + (size_t)row * 128);
  float acc[30];
#pragma unroll
  for (int j = 0; j < 30; ++j) acc[j] = 0.f;
  float ss = 0.f;
#pragma unroll 4
  for (int kk = 0; kk < 32; ++kk) {
    float4 v = h4[kk];
    ss += v.x * v.x + v.y * v.y + v.z * v.z + v.w * v.w;
#pragma unroll
    for (int j = 0; j < 30; ++j) {
      const float4 w = *(const float4*)&wc_s[j][kk * 4];
      acc[j] += v.x * w.x + v.y * w.y + v.z * w.z + v.w * w.w;
    }
  }
  float scale = 10.0f / fmaxf(sqrtf(ss), 1e-12f);
#pragma unroll
  for (int j = 0; j < 10; ++j) out1[(size_t)row * 10 + j] = scale * acc[j];
#pragma unroll
  for (int j = 0; j < 20; ++j) out2[(size_t)row * 20 + j] = scale * acc[10 + j];
}

// ---------------- fallback: atomic scatter + fp32 gemm ----------------

__global__ __launch_bounds__(256) void edge_scatter(
    const float* __restrict__ x, const int* __restrict__ ei,
    float* __restrict__ agg, float* __restrict__ deg, int E)
{
  long long total = (long long)E * 32;
  long long stride = (long long)gridDim.x * blockDim.x;
  for (long long i = (long long)blockIdx.x * blockDim.x + threadIdx.x;
       i < total; i += stride) {
    int e = (int)(i >> 5);
    int c = (int)(i & 31);
    int src = ei[e];
    int dst = ei[(size_t)E + e];
    float4 v = ((const float4*)x)[(size_t)src * 32 + c];
    float* a = agg + (size_t)dst * 128 + c * 4;
    atomicAdd(a + 0, v.x);
    atomicAdd(a + 1, v.y);
    atomicAdd(a + 2, v.z);
    atomicAdd(a + 3, v.w);
    if (c == 0) atomicAdd(deg + dst, 1.0f);
  }
}

#define FMA4(accR, wv, s) { accR[0] += (s) * wv.x; accR[1] += (s) * wv.y; \
                            accR[2] += (s) * wv.z; accR[3] += (s) * wv.w; }

__global__ __launch_bounds__(256, 2) void gemm_h(
    const float* __restrict__ x, const float* __restrict__ Wl,
    const float* __restrict__ bl, const float* __restrict__ Wr,
    const float* __restrict__ degf, float* __restrict__ aggh, int N)
{
  __shared__ float a_s[128][36];
  __shared__ float x_s[128][36];
  __shared__ float wl_s[32][128];
  __shared__ float wr_s[32][128];

  const int t = threadIdx.x;
  const int tx = t & 15;
  const int ty = t >> 4;
  const int row0 = blockIdx.x * 128;

  float acc0[8][4];
  float acc1[8][4];
#pragma unroll
  for (int r = 0; r < 8; ++r)
#pragma unroll
    for (int c = 0; c < 4; ++c) { acc0[r][c] = 0.f; acc1[r][c] = 0.f; }

  for (int kc = 0; kc < 4; ++kc) {
    __syncthreads();
#pragma unroll
    for (int j = 0; j < 4; ++j) {
      int i = t + 256 * j;
      int r = i >> 3;
      int c4 = i & 7;
      int row = row0 + r;
      float4 av = {0.f, 0.f, 0.f, 0.f};
      float4 xv = {0.f, 0.f, 0.f, 0.f};
      if (row < N) {
        float rd = 1.0f / fmaxf(degf[row], 1.0f);
        av = ((const float4*)aggh)[(size_t)row * 32 + kc * 8 + c4];
        av.x *= rd; av.y *= rd; av.z *= rd; av.w *= rd;
        xv = ((const float4*)x)[(size_t)row * 32 + kc * 8 + c4];
      }
      *(float4*)&a_s[r][c4 * 4] = av;
      *(float4*)&x_s[r][c4 * 4] = xv;
    }
#pragma unroll
    for (int j = 0; j < 4; ++j) {
      int i = t + 256 * j;
      int kk = i >> 5;
      int c4 = i & 31;
      ((float4*)wl_s[kk])[c4] = ((const float4*)Wl)[(size_t)(kc * 32 + kk) * 32 + c4];
      ((float4*)wr_s[kk])[c4] = ((const float4*)Wr)[(size_t)(kc * 32 + kk) * 32 + c4];
    }
    __syncthreads();

#pragma unroll
    for (int k4 = 0; k4 < 8; ++k4) {
      float4 wl0[4], wl1[4], wr0[4], wr1[4];
#pragma unroll
      for (int kk = 0; kk < 4; ++kk) {
        int k = k4 * 4 + kk;
        wl0[kk] = *(const float4*)&wl_s[k][tx * 4];
        wl1[kk] = *(const float4*)&wl_s[k][64 + tx * 4];
        wr0[kk] = *(const float4*)&wr_s[k][tx * 4];
        wr1[kk] = *(const float4*)&wr_s[k][64 + tx * 4];
      }
#pragma unroll
      for (int r = 0; r < 8; ++r) {
        int rr = ty + 16 * r;
        float4 a  = *(const float4*)&a_s[rr][k4 * 4];
        float4 xv = *(const float4*)&x_s[rr][k4 * 4];
        FMA4(acc0[r], wl0[0], a.x); FMA4(acc0[r], wl0[1], a.y);
        FMA4(acc0[r], wl0[2], a.z); FMA4(acc0[r], wl0[3], a.w);
        FMA4(acc0[r], wr0[0], xv.x); FMA4(acc0[r], wr0[1], xv.y);
        FMA4(acc0[r], wr0[2], xv.z); FMA4(acc0[r], wr0[3], xv.w);
        FMA4(acc1[r], wl1[0], a.x); FMA4(acc1[r], wl1[1], a.y);
        FMA4(acc1[r], wl1[2], a.z); FMA4(acc1[r], wl1[3], a.w);
        FMA4(acc1[r], wr1[0], xv.x); FMA4(acc1[r], wr1[1], xv.y);
        FMA4(acc1[r], wr1[2], xv.z); FMA4(acc1[r], wr1[3], xv.w);
      }
    }
  }

  float4 b0 = ((const float4*)bl)[tx];
  float4 b1 = ((const float4*)bl)[16 + tx];
#pragma unroll
  for (int r = 0; r < 8; ++r) {
    int row = row0 + ty + 16 * r;
    if (row < N) {
      float4 o0 = { acc0[r][0] + b0.x, acc0[r][1] + b0.y,
                    acc0[r][2] + b0.z, acc0[r][3] + b0.w };
      float4 o1 = { acc1[r][0] + b1.x, acc1[r][1] + b1.y,
                    acc1[r][2] + b1.z, acc1[r][3] + b1.w };
      ((float4*)aggh)[(size_t)row * 32 + tx] = o0;
      ((float4*)aggh)[(size_t)row * 32 + 16 + tx] = o1;
    }
  }
}

// ---------------- launch ----------------

extern "C" void kernel_launch(void* const* d_in, const int* in_sizes, int n_in,
                              void* d_out, int out_size, void* d_ws, size_t ws_size,
                              hipStream_t stream)
{
  const float* x  = (const float*)d_in[0];
  const int*   ei = (const int*)d_in[1];
  const float* Wl = (const float*)d_in[2];
  const float* bl = (const float*)d_in[3];
  const float* Wr = (const float*)d_in[4];
  const float* W1 = (const float*)d_in[5];
  const float* W2 = (const float*)d_in[6];

  const int N  = in_sizes[0] / 128;
  const int E  = in_sizes[1] / 2;
  const int c1 = in_sizes[5] / 128;
  const int c2 = in_sizes[6] / 128;
  const int nb = (N + 255) >> SH;          // 256-node buckets
  const int nbk = nb * NBLK;
  const int CH = (E + NBLK - 1) / NBLK;

  float* out1 = (float*)d_out;
  float* out2 = out1 + (size_t)N * c1;
  float* h    = out2 + (size_t)N * c2;

  size_t ints = (size_t)nbk + 256 + (N + 1) + 2 * (size_t)E;
  ints = (ints + 3) & ~(size_t)3;
  const size_t need = ints * sizeof(int)
                    + (size_t)128 * 256 * sizeof(short);      // wbT

  if (ws_size >= need && nb <= 512) {
    int* G     = (int*)d_ws;                    // nbk
    int* csum  = G + nbk;                       // 256
    int* offs  = csum + 256;                    // N+1
    int* ebuf  = offs + (N + 1);                // E packed (src<<8)|dstLow
    int* elist = ebuf + E;                      // E
    short* wbT  = (short*)((int*)d_ws + ints);  // 128*256 (16B-aligned)
    short* hs   = (short*)h;                    // interleaved [xb|aggb] rows
    const int nchunks = (nbk + SCAN_CHUNK - 1) / SCAN_CHUNK;

    conv_x_kernel<<<2048, 256, 0, stream>>>(x, hs, N * 16);
    radix_hist<<<NBLK, BLKT, 0, stream>>>(ei, G, E, nb, CH);
    scan1_kernel<<<nchunks, 256, 0, stream>>>(G, G, csum, nbk);
    scan2_kernel<<<1, 256, 0, stream>>>(csum, nchunks);
    scan3_add<<<(nbk + 255) / 256, 256, 0, stream>>>(G, csum, nbk);
    radix_scatter<<<NBLK, BLKT, 0, stream>>>(ei, G, ebuf, E, nb, CH);
    csr_finalize<<<nb, 256, 0, stream>>>(G, ebuf, offs, elist, N, E, nb);
    agg_gather_b<<<(N + 3) / 4, 256, 0, stream>>>(hs, hs, offs, elist, N);
    conv_w_kernel<<<128, 256, 0, stream>>>(Wl, Wr, wbT);
    gemm_mfma<<<(N + 127) / 128, 256, 0, stream>>>(hs, wbT, bl, h, N);
  } else {
    float* deg = out1;   // borrow out1 region (consumed before head rewrites it)
    hipMemsetAsync(h,   0, (size_t)N * 128 * sizeof(float), stream);
    hipMemsetAsync(deg, 0, (size_t)N * sizeof(float), stream);
    edge_scatter<<<4096, 256, 0, stream>>>(x, ei, h, deg, E);
    gemm_h<<<(N + 127) / 128, 256, 0, stream>>>(x, Wl, bl, Wr, deg, h, N);
  }
  head_kernel<<<(N + 255) / 256, 256, 0, stream>>>(h, W1, W2, out1, out2, N, c1, c2);
}

// Round 11
// 186.225 us; speedup vs baseline: 1.4478x; 1.0394x over previous
//
#include <hip/hip_runtime.h>
#include <math.h>

// d_out layout (floats): out1[N*10] | out2[N*20] | h[N*128]
//   h region (as shorts) = interleaved bf16 staging:
//     row r shorts [256r,256r+128)     = xb row r   (conv_x)
//     row r shorts [256r+128,256r+256) = aggb row r (agg_gather_b)
//   gemm_mfma reads block-local rows, overwrites with f32 h in-place.
// d_ws (~33MB):
//   cellcnt[NBLK*nb] | bstart[nb+1] | offs[N+1] | elist[E] | ebufC[NBLK*nb*CAP] | wbT
// Single-pass CSR: each (block,bucket) owns a private CAP=64 cell in ebufC
// (block-private 100KB regions -> no cross-XCD line sharing). Poisson(16)
// overflow prob ~1e-18/cell, clamped. Fallback: atomic-scatter fp32 path.

typedef __attribute__((ext_vector_type(8))) short s16x8;
typedef __attribute__((ext_vector_type(4))) float f32x4;

#define NBLK 256
#define BLKT 512
#define SH 8
#define BMASK 255
#define CAP 64

static __device__ __forceinline__ unsigned short f2b(float f) {
  unsigned u = __builtin_bit_cast(unsigned, f);
  u += 0x7fff + ((u >> 16) & 1);                 // round-to-nearest-even
  return (unsigned short)(u >> 16);
}
static __device__ __forceinline__ float b2f(unsigned short s) {
  unsigned u = ((unsigned)s) << 16;
  return __builtin_bit_cast(float, u);
}

// ---------------- single-pass bucketed scatter ----------------

__global__ __launch_bounds__(BLKT) void scatter_direct(
    const int* __restrict__ ei, int* __restrict__ ebufC,
    int* __restrict__ cellcnt, int* __restrict__ tot,
    int E, int nb, int CH)
{
  __shared__ int cur[512];
  const int b = blockIdx.x;
  const int t = threadIdx.x;
  for (int i = t; i < nb; i += BLKT) cur[i] = 0;
  __syncthreads();
  const int e0 = b * CH, e1 = min(E, e0 + CH);
  const size_t base = (size_t)b * nb;
  for (int e = e0 + t; e < e1; e += BLKT) {
    int src = ei[e];
    int dst = ei[(size_t)E + e];
    int k = dst >> SH;
    int pos = atomicAdd(&cur[k], 1);
    if (pos < CAP)
      ebufC[(base + k) * CAP + pos] = (src << SH) | (dst & BMASK);
  }
  __syncthreads();
  for (int i = t; i < nb; i += BLKT) {
    int c = min(cur[i], CAP);
    cellcnt[base + i] = c;
    if (c) atomicAdd(&tot[i], c);
  }
}

// single block: exclusive scan of tot[nb] -> bucket starts, bstart[nb]=E
__global__ __launch_bounds__(256) void bucket_scan(
    int* __restrict__ bstart, int nb, int E)
{
  __shared__ int s_sum[256];
  const int t = threadIdx.x;
  const int base = t * 2;
  int v0 = (base < nb) ? bstart[base] : 0;
  int v1 = (base + 1 < nb) ? bstart[base + 1] : 0;
  int s = v0 + v1;
  s_sum[t] = s;
  __syncthreads();
#pragma unroll
  for (int off = 1; off < 256; off <<= 1) {
    int add = (t >= off) ? s_sum[t - off] : 0;
    __syncthreads();
    s_sum[t] += add;
    __syncthreads();
  }
  int run = s_sum[t] - s;
  if (base < nb) bstart[base] = run;
  if (base + 1 < nb) bstart[base + 1] = run + v0;
  if (t == 255) bstart[nb] = E;
}

// one block per bucket: thread t owns cell (b=t, k); counts/prefix/cursors in LDS
__global__ __launch_bounds__(256) void csr_finalize_direct(
    const int* __restrict__ ebufC, const int* __restrict__ cellcnt,
    const int* __restrict__ bstart,
    int* __restrict__ offs, int* __restrict__ elist, int N, int E, int nb)
{
  __shared__ int ncnt[256];
  __shared__ int sc[256];
  __shared__ int ncur[256];
  const int k = blockIdx.x;
  const int t = threadIdx.x;
  const int e0 = bstart[k];

  ncnt[t] = 0;
  __syncthreads();
  // pass 1: count per node (thread t = cell of block b=t)
  const int c = cellcnt[(size_t)t * nb + k];
  const int* cell = &ebufC[((size_t)t * nb + k) * CAP];
  for (int i = 0; i < c; ++i)
    atomicAdd(&ncnt[cell[i] & BMASK], 1);
  __syncthreads();
  int v = ncnt[t];
  sc[t] = v;
  __syncthreads();
#pragma unroll
  for (int off = 1; off < 256; off <<= 1) {
    int add = (t >= off) ? sc[t - off] : 0;
    __syncthreads();
    sc[t] += add;
    __syncthreads();
  }
  int ex = e0 + sc[t] - v;
  int node = (k << SH) + t;
  if (node < N) offs[node] = ex;
  ncur[t] = ex;
  if (k == 0 && t == 0) offs[N] = E;
  __syncthreads();
  // pass 2: place
  for (int i = 0; i < c; ++i) {
    int w = cell[i];
    int pos = atomicAdd(&ncur[w & BMASK], 1);
    elist[pos] = w >> SH;
  }
}

// ---------------- bf16 x into interleaved h region ----------------

__global__ __launch_bounds__(256) void conv_x_kernel(
    const float* __restrict__ x, short* __restrict__ hs, int n8)
{
  int stride = gridDim.x * blockDim.x;
  for (int i = blockIdx.x * blockDim.x + threadIdx.x; i < n8; i += stride) {
    int row = i >> 4, seg = i & 15;
    float4 v0 = ((const float4*)x)[(size_t)row * 32 + seg * 2];
    float4 v1 = ((const float4*)x)[(size_t)row * 32 + seg * 2 + 1];
    s16x8 o;
    o[0] = (short)f2b(v0.x); o[1] = (short)f2b(v0.y);
    o[2] = (short)f2b(v0.z); o[3] = (short)f2b(v0.w);
    o[4] = (short)f2b(v1.x); o[5] = (short)f2b(v1.y);
    o[6] = (short)f2b(v1.z); o[7] = (short)f2b(v1.w);
    *(s16x8*)&hs[(size_t)row * 256 + seg * 8] = o;
  }
}

// ---------------- gather (bf16 x half, fp32 accum, mean, bf16 agg half) -----

__global__ __launch_bounds__(256) void agg_gather_b(
    const short* __restrict__ hs_in, short* __restrict__ hs_out,
    const int* __restrict__ offs, const int* __restrict__ elist, int N)
{
  const int lane = threadIdx.x & 63;
  const int row = blockIdx.x * 4 + (threadIdx.x >> 6);
  if (row >= N) return;
  const int qt = lane >> 4;     // edge slot 0..3
  const int c  = lane & 15;     // 8-bf16 segment
  const int start = offs[row], end = offs[row + 1];
  float a[8] = {0.f, 0.f, 0.f, 0.f, 0.f, 0.f, 0.f, 0.f};
  for (int j = start + qt; j < end; j += 4) {
    const s16x8 v = *(const s16x8*)&hs_in[(size_t)elist[j] * 256 + c * 8];
#pragma unroll
    for (int k = 0; k < 8; ++k) a[k] += b2f((unsigned short)v[k]);
  }
#pragma unroll
  for (int k = 0; k < 8; ++k) {
    a[k] += __shfl_xor(a[k], 16);
    a[k] += __shfl_xor(a[k], 32);
  }
  if (qt == 0) {
    float rd = 1.0f / fmaxf((float)(end - start), 1.0f);
    s16x8 o;
#pragma unroll
    for (int k = 0; k < 8; ++k) o[k] = (short)f2b(a[k] * rd);
    *(s16x8*)&hs_out[(size_t)row * 256 + 128 + c * 8] = o;
  }
}

// wbT[c][k]: k=0..127 from Wr (x half), k=128..255 from Wl (agg half)
__global__ __launch_bounds__(256) void conv_w_kernel(
    const float* __restrict__ Wl, const float* __restrict__ Wr,
    short* __restrict__ wbT)
{
  int i = blockIdx.x * blockDim.x + threadIdx.x;
  if (i < 128 * 256) {
    int c = i >> 8;
    int k = i & 255;
    float v = (k < 128) ? Wr[(size_t)k * 128 + c] : Wl[(size_t)(k - 128) * 128 + c];
    wbT[i] = (short)f2b(v);
  }
}

// ---------------- MFMA gemm: h = [x|agg] @ wbT^T + bl (in-place over hs) ----

__global__ __launch_bounds__(256, 2) void gemm_mfma(
    const short* __restrict__ hs, const short* __restrict__ wbT,
    const float* __restrict__ bl, float* __restrict__ h, int N)
{
  __shared__ short A_s[128][72];   // +8 bf16 pad
  __shared__ short B_s[128][72];   // B_s[col][k]

  const int t = threadIdx.x;
  const int lane = t & 63;
  const int wid = t >> 6;
  const int wr = wid >> 1;
  const int wc = wid & 1;
  const int row0 = blockIdx.x * 128;
  const int l15 = lane & 15;
  const int lhi = lane >> 4;

  f32x4 acc[4][4];
#pragma unroll
  for (int m = 0; m < 4; ++m)
#pragma unroll
    for (int n = 0; n < 4; ++n) acc[m][n] = (f32x4){0.f, 0.f, 0.f, 0.f};

  for (int kc = 0; kc < 4; ++kc) {
    __syncthreads();
#pragma unroll
    for (int uu = 0; uu < 4; ++uu) {
      int u = t + uu * 256;        // 0..1023
      int r = u >> 3;              // row 0..127
      int s = u & 7;               // 8-short segment 0..7
      s16x8 va = {0, 0, 0, 0, 0, 0, 0, 0};
      int grow = row0 + r;
      if (grow < N)
        va = *(const s16x8*)&hs[(size_t)grow * 256 + kc * 64 + s * 8];
      *(s16x8*)&A_s[r][s * 8] = va;
      s16x8 vb = *(const s16x8*)&wbT[(size_t)r * 256 + kc * 64 + s * 8];
      *(s16x8*)&B_s[r][s * 8] = vb;
    }
    __syncthreads();

#pragma unroll
    for (int ks = 0; ks < 64; ks += 32) {
      const int klo = ks + lhi * 8;
      s16x8 af[4], bf[4];
#pragma unroll
      for (int m = 0; m < 4; ++m)
        af[m] = *(const s16x8*)&A_s[wr * 64 + m * 16 + l15][klo];
#pragma unroll
      for (int n = 0; n < 4; ++n)
        bf[n] = *(const s16x8*)&B_s[wc * 64 + n * 16 + l15][klo];
#pragma unroll
      for (int m = 0; m < 4; ++m)
#pragma unroll
        for (int n = 0; n < 4; ++n)
          acc[m][n] = __builtin_amdgcn_mfma_f32_16x16x32_bf16(
              af[m], bf[n], acc[m][n], 0, 0, 0);
    }
  }

  // C frag mapping: col=lane&15, row=(lane>>4)*4+reg (m89-verified)
  float bcol[4];
#pragma unroll
  for (int n = 0; n < 4; ++n) bcol[n] = bl[wc * 64 + n * 16 + l15];
#pragma unroll
  for (int m = 0; m < 4; ++m) {
    int grow_base = row0 + wr * 64 + m * 16 + lhi * 4;
#pragma unroll
    for (int r = 0; r < 4; ++r) {
      int grow = grow_base + r;
      if (grow < N) {
#pragma unroll
        for (int n = 0; n < 4; ++n) {
          int col = wc * 64 + n * 16 + l15;
          h[(size_t)grow * 128 + col] = acc[m][n][r] + bcol[n];
        }
      }
    }
  }
}

// ---------------- heads (one thread per row, wc_s broadcast) ----------------

__global__ __launch_bounds__(256) void head_kernel(
    const float* __restrict__ h, const float* __restrict__ W1,
    const float* __restrict__ W2,
    float* __restrict__ out1, float* __restrict__ out2,
    int N, int c1, int c2)
{
  __shared__ float wc_s[30][132];
  __shared__ float wnorm[30];
  const int nc = c1 + c2;

  for (int i = threadIdx.x; i < nc * 128; i += 256) {
    int j = i >> 7, l = i & 127;
    wc_s[j][l] = (j < c1) ? W1[(size_t)l * c1 + j]
                          : W2[(size_t)l * c2 + (j - c1)];
  }
  __syncthreads();
  if (threadIdx.x < nc) {
    float ss = 0.f;
    for (int l = 0; l < 128; ++l) { float v = wc_s[threadIdx.x][l]; ss += v * v; }
    wnorm[threadIdx.x] = 1.0f / fmaxf(sqrtf(ss), 1e-12f);
  }
  __syncthreads();
  for (int i = threadIdx.x; i < nc * 128; i += 256) {
    int j = i >> 7;
    wc_s[j][i & 127] *= wnorm[j];
  }
  __syncthreads();

  int row = blockIdx.x * 256 + threadIdx.x;
  if (row >= N) return;
  const float4* h4 = (const float4*)(h + (size_t)row * 128);
  float acc[30];
#pragma unroll
  for (int j = 0; j < 30; ++j) acc[j] = 0.f;
  float ss = 0.f;
#pragma unroll 4
  for (int kk = 0; kk < 32; ++kk) {
    float4 v = h4[kk];
    ss += v.x * v.x + v.y * v.y + v.z * v.z + v.w * v.w;
#pragma unroll
    for (int j = 0; j < 30; ++j) {
      const float4 w = *(const float4*)&wc_s[j][kk * 4];
      acc[j] += v.x * w.x + v.y * w.y + v.z * w.z + v.w * w.w;
    }
  }
  float scale = 10.0f / fmaxf(sqrtf(ss), 1e-12f);
#pragma unroll
  for (int j = 0; j < 10; ++j) out1[(size_t)row * 10 + j] = scale * acc[j];
#pragma unroll
  for (int j = 0; j < 20; ++j) out2[(size_t)row * 20 + j] = scale * acc[10 + j];
}

// ---------------- fallback: atomic scatter + fp32 gemm ----------------

__global__ __launch_bounds__(256) void edge_scatter(
    const float* __restrict__ x, const int* __restrict__ ei,
    float* __restrict__ agg, float* __restrict__ deg, int E)
{
  long long total = (long long)E * 32;
  long long stride = (long long)gridDim.x * blockDim.x;
  for (long long i = (long long)blockIdx.x * blockDim.x + threadIdx.x;
       i < total; i += stride) {
    int e = (int)(i >> 5);
    int c = (int)(i & 31);
    int src = ei[e];
    int dst = ei[(size_t)E + e];
    float4 v = ((const float4*)x)[(size_t)src * 32 + c];
    float* a = agg + (size_t)dst * 128 + c * 4;
    atomicAdd(a + 0, v.x);
    atomicAdd(a + 1, v.y);
    atomicAdd(a + 2, v.z);
    atomicAdd(a + 3, v.w);
    if (c == 0) atomicAdd(deg + dst, 1.0f);
  }
}

#define FMA4(accR, wv, s) { accR[0] += (s) * wv.x; accR[1] += (s) * wv.y; \
                            accR[2] += (s) * wv.z; accR[3] += (s) * wv.w; }

__global__ __launch_bounds__(256, 2) void gemm_h(
    const float* __restrict__ x, const float* __restrict__ Wl,
    const float* __restrict__ bl, const float* __restrict__ Wr,
    const float* __restrict__ degf, float* __restrict__ aggh, int N)
{
  __shared__ float a_s[128][36];
  __shared__ float x_s[128][36];
  __shared__ float wl_s[32][128];
  __shared__ float wr_s[32][128];

  const int t = threadIdx.x;
  const int tx = t & 15;
  const int ty = t >> 4;
  const int row0 = blockIdx.x * 128;

  float acc0[8][4];
  float acc1[8][4];
#pragma unroll
  for (int r = 0; r < 8; ++r)
#pragma unroll
    for (int c = 0; c < 4; ++c) { acc0[r][c] = 0.f; acc1[r][c] = 0.f; }

  for (int kc = 0; kc < 4; ++kc) {
    __syncthreads();
#pragma unroll
    for (int j = 0; j < 4; ++j) {
      int i = t + 256 * j;
      int r = i >> 3;
      int c4 = i & 7;
      int row = row0 + r;
      float4 av = {0.f, 0.f, 0.f, 0.f};
      float4 xv = {0.f, 0.f, 0.f, 0.f};
      if (row < N) {
        float rd = 1.0f / fmaxf(degf[row], 1.0f);
        av = ((const float4*)aggh)[(size_t)row * 32 + kc * 8 + c4];
        av.x *= rd; av.y *= rd; av.z *= rd; av.w *= rd;
        xv = ((const float4*)x)[(size_t)row * 32 + kc * 8 + c4];
      }
      *(float4*)&a_s[r][c4 * 4] = av;
      *(float4*)&x_s[r][c4 * 4] = xv;
    }
#pragma unroll
    for (int j = 0; j < 4; ++j) {
      int i = t + 256 * j;
      int kk = i >> 5;
      int c4 = i & 31;
      ((float4*)wl_s[kk])[c4] = ((const float4*)Wl)[(size_t)(kc * 32 + kk) * 32 + c4];
      ((float4*)wr_s[kk])[c4] = ((const float4*)Wr)[(size_t)(kc * 32 + kk) * 32 + c4];
    }
    __syncthreads();

#pragma unroll
    for (int k4 = 0; k4 < 8; ++k4) {
      float4 wl0[4], wl1[4], wr0[4], wr1[4];
#pragma unroll
      for (int kk = 0; kk < 4; ++kk) {
        int k = k4 * 4 + kk;
        wl0[kk] = *(const float4*)&wl_s[k][tx * 4];
        wl1[kk] = *(const float4*)&wl_s[k][64 + tx * 4];
        wr0[kk] = *(const float4*)&wr_s[k][tx * 4];
        wr1[kk] = *(const float4*)&wr_s[k][64 + tx * 4];
      }
#pragma unroll
      for (int r = 0; r < 8; ++r) {
        int rr = ty + 16 * r;
        float4 a  = *(const float4*)&a_s[rr][k4 * 4];
        float4 xv = *(const float4*)&x_s[rr][k4 * 4];
        FMA4(acc0[r], wl0[0], a.x); FMA4(acc0[r], wl0[1], a.y);
        FMA4(acc0[r], wl0[2], a.z); FMA4(acc0[r], wl0[3], a.w);
        FMA4(acc0[r], wr0[0], xv.x); FMA4(acc0[r], wr0[1], xv.y);
        FMA4(acc0[r], wr0[2], xv.z); FMA4(acc0[r], wr0[3], xv.w);
        FMA4(acc1[r], wl1[0], a.x); FMA4(acc1[r], wl1[1], a.y);
        FMA4(acc1[r], wl1[2], a.z); FMA4(acc1[r], wl1[3], a.w);
        FMA4(acc1[r], wr1[0], xv.x); FMA4(acc1[r], wr1[1], xv.y);
        FMA4(acc1[r], wr1[2], xv.z); FMA4(acc1[r], wr1[3], xv.w);
      }
    }
  }

  float4 b0 = ((const float4*)bl)[tx];
  float4 b1 = ((const float4*)bl)[16 + tx];
#pragma unroll
  for (int r = 0; r < 8; ++r) {
    int row = row0 + ty + 16 * r;
    if (row < N) {
      float4 o0 = { acc0[r][0] + b0.x, acc0[r][1] + b0.y,
                    acc0[r][2] + b0.z, acc0[r][3] + b0.w };
      float4 o1 = { acc1[r][0] + b1.x, acc1[r][1] + b1.y,
                    acc1[r][2] + b1.z, acc1[r][3] + b1.w };
      ((float4*)aggh)[(size_t)row * 32 + tx] = o0;
      ((float4*)aggh)[(size_t)row * 32 + 16 + tx] = o1;
    }
  }
}

// ---------------- launch ----------------

extern "C" void kernel_launch(void* const* d_in, const int* in_sizes, int n_in,
                              void* d_out, int out_size, void* d_ws, size_t ws_size,
                              hipStream_t stream)
{
  const float* x  = (const float*)d_in[0];
  const int*   ei = (const int*)d_in[1];
  const float* Wl = (const float*)d_in[2];
  const float* bl = (const float*)d_in[3];
  const float* Wr = (const float*)d_in[4];
  const float* W1 = (const float*)d_in[5];
  const float* W2 = (const float*)d_in[6];

  const int N  = in_sizes[0] / 128;
  const int E  = in_sizes[1] / 2;
  const int c1 = in_sizes[5] / 128;
  const int c2 = in_sizes[6] / 128;
  const int nb = (N + 255) >> SH;          // 256-node buckets
  const int CH = (E + NBLK - 1) / NBLK;    // edges per scatter block

  float* out1 = (float*)d_out;
  float* out2 = out1 + (size_t)N * c1;
  float* h    = out2 + (size_t)N * c2;

  size_t ints = (size_t)NBLK * nb            // cellcnt
              + (nb + 1)                     // bstart
              + (N + 1)                      // offs
              + (size_t)E                    // elist
              + (size_t)NBLK * nb * CAP;     // ebufC
  ints = (ints + 3) & ~(size_t)3;
  const size_t need = ints * sizeof(int)
                    + (size_t)128 * 256 * sizeof(short);      // wbT

  // cell-capacity check: edges/block CH with CAP slack (Poisson tail ~1e-18)
  if (ws_size >= need && nb <= 512 && CH / nb < CAP / 2) {
    int* cellcnt = (int*)d_ws;                       // NBLK*nb
    int* bstart  = cellcnt + (size_t)NBLK * nb;      // nb+1 (doubles as totals)
    int* offs    = bstart + (nb + 1);                // N+1
    int* elist   = offs + (N + 1);                   // E
    int* ebufC   = elist + E;                        // NBLK*nb*CAP
    short* wbT   = (short*)((int*)d_ws + ints);      // 128*256 (16B-aligned)
    short* hs    = (short*)h;                        // interleaved [xb|aggb]

    hipMemsetAsync(bstart, 0, (size_t)(nb + 1) * sizeof(int), stream);
    conv_x_kernel<<<2048, 256, 0, stream>>>(x, hs, N * 16);
    scatter_direct<<<NBLK, BLKT, 0, stream>>>(ei, ebufC, cellcnt, bstart, E, nb, CH);
    bucket_scan<<<1, 256, 0, stream>>>(bstart, nb, E);
    csr_finalize_direct<<<nb, 256, 0, stream>>>(ebufC, cellcnt, bstart,
                                                offs, elist, N, E, nb);
    agg_gather_b<<<(N + 3) / 4, 256, 0, stream>>>(hs, hs, offs, elist, N);
    conv_w_kernel<<<128, 256, 0, stream>>>(Wl, Wr, wbT);
    gemm_mfma<<<(N + 127) / 128, 256, 0, stream>>>(hs, wbT, bl, h, N);
  } else {
    float* deg = out1;   // borrow out1 region (consumed before head rewrites it)
    hipMemsetAsync(h,   0, (size_t)N * 128 * sizeof(float), stream);
    hipMemsetAsync(deg, 0, (size_t)N * sizeof(float), stream);
    edge_scatter<<<4096, 256, 0, stream>>>(x, ei, h, deg, E);
    gemm_h<<<(N + 127) / 128, 256, 0, stream>>>(x, Wl, bl, Wr, deg, h, N);
  }
  head_kernel<<<(N + 255) / 256, 256, 0, stream>>>(h, W1, W2, out1, out2, N, c1, c2);
}

// Round 12
// 172.469 us; speedup vs baseline: 1.5633x; 1.0798x over previous
//
#include <hip/hip_runtime.h>
#include <math.h>

// d_out layout (floats): out1[N*10] | out2[N*20] | h[N*128]
//   h region (as shorts) = interleaved bf16 staging:
//     row r shorts [256r,256r+128)     = xb row r   (conv_x)
//     row r shorts [256r+128,256r+256) = aggb row r (agg_gather_b)
//   gemm_mfma reads block-local rows, overwrites with f32 h in-place.
// d_ws (~33MB):
//   cellcnt[NBLK*nb] | bstart[nb+1] | offs[N+1] | elist[E] | ebufC[NBLK*nb*CAP] | wbT
// Single-pass CSR: each (block,bucket) owns a private CAP=64 cell in ebufC.
// conv_x also converts wbT and zeroes bstart (extra blocks) - 2 fewer launches.
// Fallback: atomic-scatter fp32 path.

typedef __attribute__((ext_vector_type(8))) short s16x8;
typedef __attribute__((ext_vector_type(4))) float f32x4;

#define NBLK 256
#define BLKT 512
#define SH 8
#define BMASK 255
#define CAP 64

static __device__ __forceinline__ unsigned short f2b(float f) {
  unsigned u = __builtin_bit_cast(unsigned, f);
  u += 0x7fff + ((u >> 16) & 1);                 // round-to-nearest-even
  return (unsigned short)(u >> 16);
}
static __device__ __forceinline__ float b2f(unsigned short s) {
  unsigned u = ((unsigned)s) << 16;
  return __builtin_bit_cast(float, u);
}

// ---------------- single-pass bucketed scatter ----------------

__global__ __launch_bounds__(BLKT) void scatter_direct(
    const int* __restrict__ ei, int* __restrict__ ebufC,
    int* __restrict__ cellcnt, int* __restrict__ tot,
    int E, int nb, int CH)
{
  __shared__ int cur[512];
  const int b = blockIdx.x;
  const int t = threadIdx.x;
  for (int i = t; i < nb; i += BLKT) cur[i] = 0;
  __syncthreads();
  const int e0 = b * CH, e1 = min(E, e0 + CH);
  const size_t base = (size_t)b * nb;
  for (int e = e0 + t; e < e1; e += BLKT) {
    int src = ei[e];
    int dst = ei[(size_t)E + e];
    int k = dst >> SH;
    int pos = atomicAdd(&cur[k], 1);
    if (pos < CAP)
      ebufC[(base + k) * CAP + pos] = (src << SH) | (dst & BMASK);
  }
  __syncthreads();
  for (int i = t; i < nb; i += BLKT) {
    int c = min(cur[i], CAP);
    cellcnt[base + i] = c;
    if (c) atomicAdd(&tot[i], c);
  }
}

// single block: exclusive scan of tot[nb] -> bucket starts, bstart[nb]=E
__global__ __launch_bounds__(256) void bucket_scan(
    int* __restrict__ bstart, int nb, int E)
{
  __shared__ int s_sum[256];
  const int t = threadIdx.x;
  const int base = t * 2;
  int v0 = (base < nb) ? bstart[base] : 0;
  int v1 = (base + 1 < nb) ? bstart[base + 1] : 0;
  int s = v0 + v1;
  s_sum[t] = s;
  __syncthreads();
#pragma unroll
  for (int off = 1; off < 256; off <<= 1) {
    int add = (t >= off) ? s_sum[t - off] : 0;
    __syncthreads();
    s_sum[t] += add;
    __syncthreads();
  }
  int run = s_sum[t] - s;
  if (base < nb) bstart[base] = run;
  if (base + 1 < nb) bstart[base + 1] = run + v0;
  if (t == 255) bstart[nb] = E;
}

// one block per bucket: thread t owns cell (b=t, k); counts/prefix/cursors in LDS
__global__ __launch_bounds__(256) void csr_finalize_direct(
    const int* __restrict__ ebufC, const int* __restrict__ cellcnt,
    const int* __restrict__ bstart,
    int* __restrict__ offs, int* __restrict__ elist, int N, int E, int nb)
{
  __shared__ int ncnt[256];
  __shared__ int sc[256];
  __shared__ int ncur[256];
  const int k = blockIdx.x;
  const int t = threadIdx.x;
  const int e0 = bstart[k];

  ncnt[t] = 0;
  __syncthreads();
  const int c = cellcnt[(size_t)t * nb + k];
  const int* cell = &ebufC[((size_t)t * nb + k) * CAP];
  for (int i = 0; i < c; ++i)
    atomicAdd(&ncnt[cell[i] & BMASK], 1);
  __syncthreads();
  int v = ncnt[t];
  sc[t] = v;
  __syncthreads();
#pragma unroll
  for (int off = 1; off < 256; off <<= 1) {
    int add = (t >= off) ? sc[t - off] : 0;
    __syncthreads();
    sc[t] += add;
    __syncthreads();
  }
  int ex = e0 + sc[t] - v;
  int node = (k << SH) + t;
  if (node < N) offs[node] = ex;
  ncur[t] = ex;
  if (k == 0 && t == 0) offs[N] = E;
  __syncthreads();
  for (int i = 0; i < c; ++i) {
    int w = cell[i];
    int pos = atomicAdd(&ncur[w & BMASK], 1);
    elist[pos] = w >> SH;
  }
}

// ---------------- conv_x (+ fused wbT conversion + bstart zero) ----------------
// blocks [0,2048): x -> bf16 into interleaved hs
// blocks [2048,2064): wbT[c][k] (k<128 from Wr, k>=128 from Wl)
// block 2064: zero bstart[nb+1]

__global__ __launch_bounds__(256) void conv_x_kernel(
    const float* __restrict__ x, short* __restrict__ hs, int n8,
    const float* __restrict__ Wl, const float* __restrict__ Wr,
    short* __restrict__ wbT, int* __restrict__ bstart, int nbp1)
{
  const int b = blockIdx.x;
  if (b < 2048) {
    const int stride = 2048 * 256;
    for (int i = b * 256 + threadIdx.x; i < n8; i += stride) {
      int row = i >> 4, seg = i & 15;
      float4 v0 = ((const float4*)x)[(size_t)row * 32 + seg * 2];
      float4 v1 = ((const float4*)x)[(size_t)row * 32 + seg * 2 + 1];
      s16x8 o;
      o[0] = (short)f2b(v0.x); o[1] = (short)f2b(v0.y);
      o[2] = (short)f2b(v0.z); o[3] = (short)f2b(v0.w);
      o[4] = (short)f2b(v1.x); o[5] = (short)f2b(v1.y);
      o[6] = (short)f2b(v1.z); o[7] = (short)f2b(v1.w);
      *(s16x8*)&hs[(size_t)row * 256 + seg * 8] = o;
    }
  } else if (b < 2064) {
    int i0 = (b - 2048) * 2048 + threadIdx.x;
#pragma unroll
    for (int u = 0; u < 8; ++u) {
      int i = i0 + u * 256;          // 0..32767
      int c = i >> 8;
      int k = i & 255;
      float v = (k < 128) ? Wr[(size_t)k * 128 + c]
                          : Wl[(size_t)(k - 128) * 128 + c];
      wbT[i] = (short)f2b(v);
    }
  } else {
    for (int i = threadIdx.x; i < nbp1; i += 256) bstart[i] = 0;
  }
}

// ---------------- gather: 2-deep pipelined (bf16, fp32 accum, mean) ---------

__global__ __launch_bounds__(256) void agg_gather_b(
    const short* __restrict__ hs_in, short* __restrict__ hs_out,
    const int* __restrict__ offs, const int* __restrict__ elist, int N)
{
  const int lane = threadIdx.x & 63;
  const int row = blockIdx.x * 4 + (threadIdx.x >> 6);
  if (row >= N) return;
  const int qt = lane >> 4;     // edge slot 0..3
  const int c  = lane & 15;     // 8-bf16 segment
  const int start = offs[row], end = offs[row + 1];
  float a[8] = {0.f, 0.f, 0.f, 0.f, 0.f, 0.f, 0.f, 0.f};

  int j = start + qt;
  s16x8 v0 = {0, 0, 0, 0, 0, 0, 0, 0};
  if (j < end)
    v0 = *(const s16x8*)&hs_in[(size_t)elist[j] * 256 + c * 8];
  while (j < end) {
    int j1 = j + 4;
    s16x8 v1 = {0, 0, 0, 0, 0, 0, 0, 0};
    if (j1 < end)
      v1 = *(const s16x8*)&hs_in[(size_t)elist[j1] * 256 + c * 8];  // in flight
#pragma unroll
    for (int k = 0; k < 8; ++k) a[k] += b2f((unsigned short)v0[k]);
    v0 = v1;
    j = j1;
  }
#pragma unroll
  for (int k = 0; k < 8; ++k) {
    a[k] += __shfl_xor(a[k], 16);
    a[k] += __shfl_xor(a[k], 32);
  }
  if (qt == 0) {
    float rd = 1.0f / fmaxf((float)(end - start), 1.0f);
    s16x8 o;
#pragma unroll
    for (int k = 0; k < 8; ++k) o[k] = (short)f2b(a[k] * rd);
    *(s16x8*)&hs_out[(size_t)row * 256 + 128 + c * 8] = o;
  }
}

// ---------------- MFMA gemm: h = [x|agg] @ wbT^T + bl (in-place over hs) ----

__global__ __launch_bounds__(256, 4) void gemm_mfma(
    const short* __restrict__ hs, const short* __restrict__ wbT,
    const float* __restrict__ bl, float* __restrict__ h, int N)
{
  __shared__ short A_s[128][72];   // +8 bf16 pad
  __shared__ short B_s[128][72];   // B_s[col][k]

  const int t = threadIdx.x;
  const int lane = t & 63;
  const int wid = t >> 6;
  const int wr = wid >> 1;
  const int wc = wid & 1;
  const int row0 = blockIdx.x * 128;
  const int l15 = lane & 15;
  const int lhi = lane >> 4;

  f32x4 acc[4][4];
#pragma unroll
  for (int m = 0; m < 4; ++m)
#pragma unroll
    for (int n = 0; n < 4; ++n) acc[m][n] = (f32x4){0.f, 0.f, 0.f, 0.f};

  for (int kc = 0; kc < 4; ++kc) {
    __syncthreads();
#pragma unroll
    for (int uu = 0; uu < 4; ++uu) {
      int u = t + uu * 256;        // 0..1023
      int r = u >> 3;              // row 0..127
      int s = u & 7;               // 8-short segment 0..7
      s16x8 va = {0, 0, 0, 0, 0, 0, 0, 0};
      int grow = row0 + r;
      if (grow < N)
        va = *(const s16x8*)&hs[(size_t)grow * 256 + kc * 64 + s * 8];
      *(s16x8*)&A_s[r][s * 8] = va;
      s16x8 vb = *(const s16x8*)&wbT[(size_t)r * 256 + kc * 64 + s * 8];
      *(s16x8*)&B_s[r][s * 8] = vb;
    }
    __syncthreads();

#pragma unroll
    for (int ks = 0; ks < 64; ks += 32) {
      const int klo = ks + lhi * 8;
      s16x8 af[4], bf[4];
#pragma unroll
      for (int m = 0; m < 4; ++m)
        af[m] = *(const s16x8*)&A_s[wr * 64 + m * 16 + l15][klo];
#pragma unroll
      for (int n = 0; n < 4; ++n)
        bf[n] = *(const s16x8*)&B_s[wc * 64 + n * 16 + l15][klo];
#pragma unroll
      for (int m = 0; m < 4; ++m)
#pragma unroll
        for (int n = 0; n < 4; ++n)
          acc[m][n] = __builtin_amdgcn_mfma_f32_16x16x32_bf16(
              af[m], bf[n], acc[m][n], 0, 0, 0);
    }
  }

  // C frag mapping: col=lane&15, row=(lane>>4)*4+reg (m89-verified)
  float bcol[4];
#pragma unroll
  for (int n = 0; n < 4; ++n) bcol[n] = bl[wc * 64 + n * 16 + l15];
#pragma unroll
  for (int m = 0; m < 4; ++m) {
    int grow_base = row0 + wr * 64 + m * 16 + lhi * 4;
#pragma unroll
    for (int r = 0; r < 4; ++r) {
      int grow = grow_base + r;
      if (grow < N) {
#pragma unroll
        for (int n = 0; n < 4; ++n) {
          int col = wc * 64 + n * 16 + l15;
          h[(size_t)grow * 128 + col] = acc[m][n][r] + bcol[n];
        }
      }
    }
  }
}

// ---------------- heads (one thread per row, wc_s broadcast) ----------------

__global__ __launch_bounds__(256) void head_kernel(
    const float* __restrict__ h, const float* __restrict__ W1,
    const float* __restrict__ W2,
    float* __restrict__ out1, float* __restrict__ out2,
    int N, int c1, int c2)
{
  __shared__ float wc_s[30][132];
  __shared__ float wnorm[30];
  const int nc = c1 + c2;

  for (int i = threadIdx.x; i < nc * 128; i += 256) {
    int j = i >> 7, l = i & 127;
    wc_s[j][l] = (j < c1) ? W1[(size_t)l * c1 + j]
                          : W2[(size_t)l * c2 + (j - c1)];
  }
  __syncthreads();
  if (threadIdx.x < nc) {
    float ss = 0.f;
    for (int l = 0; l < 128; ++l) { float v = wc_s[threadIdx.x][l]; ss += v * v; }
    wnorm[threadIdx.x] = 1.0f / fmaxf(sqrtf(ss), 1e-12f);
  }
  __syncthreads();
  for (int i = threadIdx.x; i < nc * 128; i += 256) {
    int j = i >> 7;
    wc_s[j][i & 127] *= wnorm[j];
  }
  __syncthreads();

  int row = blockIdx.x * 256 + threadIdx.x;
  if (row >= N) return;
  const float4* h4 = (const float4*)(h + (size_t)row * 128);
  float acc[30];
#pragma unroll
  for (int j = 0; j < 30; ++j) acc[j] = 0.f;
  float ss = 0.f;
#pragma unroll 4
  for (int kk = 0; kk < 32; ++kk) {
    float4 v = h4[kk];
    ss += v.x * v.x + v.y * v.y + v.z * v.z + v.w * v.w;
#pragma unroll
    for (int j = 0; j < 30; ++j) {
      const float4 w = *(const float4*)&wc_s[j][kk * 4];
      acc[j] += v.x * w.x + v.y * w.y + v.z * w.z + v.w * w.w;
    }
  }
  float scale = 10.0f / fmaxf(sqrtf(ss), 1e-12f);
#pragma unroll
  for (int j = 0; j < 10; ++j) out1[(size_t)row * 10 + j] = scale * acc[j];
#pragma unroll
  for (int j = 0; j < 20; ++j) out2[(size_t)row * 20 + j] = scale * acc[10 + j];
}

// ---------------- fallback: atomic scatter + fp32 gemm ----------------

__global__ __launch_bounds__(256) void edge_scatter(
    const float* __restrict__ x, const int* __restrict__ ei,
    float* __restrict__ agg, float* __restrict__ deg, int E)
{
  long long total = (long long)E * 32;
  long long stride = (long long)gridDim.x * blockDim.x;
  for (long long i = (long long)blockIdx.x * blockDim.x + threadIdx.x;
       i < total; i += stride) {
    int e = (int)(i >> 5);
    int c = (int)(i & 31);
    int src = ei[e];
    int dst = ei[(size_t)E + e];
    float4 v = ((const float4*)x)[(size_t)src * 32 + c];
    float* a = agg + (size_t)dst * 128 + c * 4;
    atomicAdd(a + 0, v.x);
    atomicAdd(a + 1, v.y);
    atomicAdd(a + 2, v.z);
    atomicAdd(a + 3, v.w);
    if (c == 0) atomicAdd(deg + dst, 1.0f);
  }
}

#define FMA4(accR, wv, s) { accR[0] += (s) * wv.x; accR[1] += (s) * wv.y; \
                            accR[2] += (s) * wv.z; accR[3] += (s) * wv.w; }

__global__ __launch_bounds__(256, 2) void gemm_h(
    const float* __restrict__ x, const float* __restrict__ Wl,
    const float* __restrict__ bl, const float* __restrict__ Wr,
    const float* __restrict__ degf, float* __restrict__ aggh, int N)
{
  __shared__ float a_s[128][36];
  __shared__ float x_s[128][36];
  __shared__ float wl_s[32][128];
  __shared__ float wr_s[32][128];

  const int t = threadIdx.x;
  const int tx = t & 15;
  const int ty = t >> 4;
  const int row0 = blockIdx.x * 128;

  float acc0[8][4];
  float acc1[8][4];
#pragma unroll
  for (int r = 0; r < 8; ++r)
#pragma unroll
    for (int c = 0; c < 4; ++c) { acc0[r][c] = 0.f; acc1[r][c] = 0.f; }

  for (int kc = 0; kc < 4; ++kc) {
    __syncthreads();
#pragma unroll
    for (int j = 0; j < 4; ++j) {
      int i = t + 256 * j;
      int r = i >> 3;
      int c4 = i & 7;
      int row = row0 + r;
      float4 av = {0.f, 0.f, 0.f, 0.f};
      float4 xv = {0.f, 0.f, 0.f, 0.f};
      if (row < N) {
        float rd = 1.0f / fmaxf(degf[row], 1.0f);
        av = ((const float4*)aggh)[(size_t)row * 32 + kc * 8 + c4];
        av.x *= rd; av.y *= rd; av.z *= rd; av.w *= rd;
        xv = ((const float4*)x)[(size_t)row * 32 + kc * 8 + c4];
      }
      *(float4*)&a_s[r][c4 * 4] = av;
      *(float4*)&x_s[r][c4 * 4] = xv;
    }
#pragma unroll
    for (int j = 0; j < 4; ++j) {
      int i = t + 256 * j;
      int kk = i >> 5;
      int c4 = i & 31;
      ((float4*)wl_s[kk])[c4] = ((const float4*)Wl)[(size_t)(kc * 32 + kk) * 32 + c4];
      ((float4*)wr_s[kk])[c4] = ((const float4*)Wr)[(size_t)(kc * 32 + kk) * 32 + c4];
    }
    __syncthreads();

#pragma unroll
    for (int k4 = 0; k4 < 8; ++k4) {
      float4 wl0[4], wl1[4], wr0[4], wr1[4];
#pragma unroll
      for (int kk = 0; kk < 4; ++kk) {
        int k = k4 * 4 + kk;
        wl0[kk] = *(const float4*)&wl_s[k][tx * 4];
        wl1[kk] = *(const float4*)&wl_s[k][64 + tx * 4];
        wr0[kk] = *(const float4*)&wr_s[k][tx * 4];
        wr1[kk] = *(const float4*)&wr_s[k][64 + tx * 4];
      }
#pragma unroll
      for (int r = 0; r < 8; ++r) {
        int rr = ty + 16 * r;
        float4 a  = *(const float4*)&a_s[rr][k4 * 4];
        float4 xv = *(const float4*)&x_s[rr][k4 * 4];
        FMA4(acc0[r], wl0[0], a.x); FMA4(acc0[r], wl0[1], a.y);
        FMA4(acc0[r], wl0[2], a.z); FMA4(acc0[r], wl0[3], a.w);
        FMA4(acc0[r], wr0[0], xv.x); FMA4(acc0[r], wr0[1], xv.y);
        FMA4(acc0[r], wr0[2], xv.z); FMA4(acc0[r], wr0[3], xv.w);
        FMA4(acc1[r], wl1[0], a.x); FMA4(acc1[r], wl1[1], a.y);
        FMA4(acc1[r], wl1[2], a.z); FMA4(acc1[r], wl1[3], a.w);
        FMA4(acc1[r], wr1[0], xv.x); FMA4(acc1[r], wr1[1], xv.y);
        FMA4(acc1[r], wr1[2], xv.z); FMA4(acc1[r], wr1[3], xv.w);
      }
    }
  }

  float4 b0 = ((const float4*)bl)[tx];
  float4 b1 = ((const float4*)bl)[16 + tx];
#pragma unroll
  for (int r = 0; r < 8; ++r) {
    int row = row0 + ty + 16 * r;
    if (row < N) {
      float4 o0 = { acc0[r][0] + b0.x, acc0[r][1] + b0.y,
                    acc0[r][2] + b0.z, acc0[r][3] + b0.w };
      float4 o1 = { acc1[r][0] + b1.x, acc1[r][1] + b1.y,
                    acc1[r][2] + b1.z, acc1[r][3] + b1.w };
      ((float4*)aggh)[(size_t)row * 32 + tx] = o0;
      ((float4*)aggh)[(size_t)row * 32 + 16 + tx] = o1;
    }
  }
}

// ---------------- launch ----------------

extern "C" void kernel_launch(void* const* d_in, const int* in_sizes, int n_in,
                              void* d_out, int out_size, void* d_ws, size_t ws_size,
                              hipStream_t stream)
{
  const float* x  = (const float*)d_in[0];
  const int*   ei = (const int*)d_in[1];
  const float* Wl = (const float*)d_in[2];
  const float* bl = (const float*)d_in[3];
  const float* Wr = (const float*)d_in[4];
  const float* W1 = (const float*)d_in[5];
  const float* W2 = (const float*)d_in[6];

  const int N  = in_sizes[0] / 128;
  const int E  = in_sizes[1] / 2;
  const int c1 = in_sizes[5] / 128;
  const int c2 = in_sizes[6] / 128;
  const int nb = (N + 255) >> SH;          // 256-node buckets
  const int CH = (E + NBLK - 1) / NBLK;    // edges per scatter block

  float* out1 = (float*)d_out;
  float* out2 = out1 + (size_t)N * c1;
  float* h    = out2 + (size_t)N * c2;

  size_t ints = (size_t)NBLK * nb            // cellcnt
              + (nb + 1)                     // bstart
              + (N + 1)                      // offs
              + (size_t)E                    // elist
              + (size_t)NBLK * nb * CAP;     // ebufC
  ints = (ints + 3) & ~(size_t)3;
  const size_t need = ints * sizeof(int)
                    + (size_t)128 * 256 * sizeof(short);      // wbT

  if (ws_size >= need && nb <= 512 && CH / nb < CAP / 2) {
    int* cellcnt = (int*)d_ws;                       // NBLK*nb
    int* bstart  = cellcnt + (size_t)NBLK * nb;      // nb+1 (doubles as totals)
    int* offs    = bstart + (nb + 1);                // N+1
    int* elist   = offs + (N + 1);                   // E
    int* ebufC   = elist + E;                        // NBLK*nb*CAP
    short* wbT   = (short*)((int*)d_ws + ints);      // 128*256 (16B-aligned)
    short* hs    = (short*)h;                        // interleaved [xb|aggb]

    conv_x_kernel<<<2065, 256, 0, stream>>>(x, hs, N * 16, Wl, Wr, wbT,
                                            bstart, nb + 1);
    scatter_direct<<<NBLK, BLKT, 0, stream>>>(ei, ebufC, cellcnt, bstart, E, nb, CH);
    bucket_scan<<<1, 256, 0, stream>>>(bstart, nb, E);
    csr_finalize_direct<<<nb, 256, 0, stream>>>(ebufC, cellcnt, bstart,
                                                offs, elist, N, E, nb);
    agg_gather_b<<<(N + 3) / 4, 256, 0, stream>>>(hs, hs, offs, elist, N);
    gemm_mfma<<<(N + 127) / 128, 256, 0, stream>>>(hs, wbT, bl, h, N);
  } else {
    float* deg = out1;   // borrow out1 region (consumed before head rewrites it)
    hipMemsetAsync(h,   0, (size_t)N * 128 * sizeof(float), stream);
    hipMemsetAsync(deg, 0, (size_t)N * sizeof(float), stream);
    edge_scatter<<<4096, 256, 0, stream>>>(x, ei, h, deg, E);
    gemm_h<<<(N + 127) / 128, 256, 0, stream>>>(x, Wl, bl, Wr, deg, h, N);
  }
  head_kernel<<<(N + 255) / 256, 256, 0, stream>>>(h, W1, W2, out1, out2, N, c1, c2);
}